// Round 1
// baseline (98.236 us; speedup 1.0000x reference)
//
#include <hip/hip_runtime.h>
#include <math.h>

// Problem constants (fixed by the reference).
#define BB 4
#define SS 2048
#define DD 16
#define HH 16
#define NCHUNK 8           // attention blocks per (b,h)
#define BHS (BB * HH * SS) // 131072 elements per Q/K/V plane

#if defined(__has_builtin)
#if __has_builtin(__builtin_amdgcn_exp2f)
#define EXP2(x) __builtin_amdgcn_exp2f(x)
#else
#define EXP2(x) exp2f(x)
#endif
#else
#define EXP2(x) exp2f(x)
#endif

#define LOG2E 1.44269504088896340736f

// ---------------------------------------------------------------------------
// Kernel A: qkv = x @ w_qkv + b_qkv, stored transposed as Q/K/V[b][h][s].
// grid = B*S/256 = 32 blocks, 256 threads; one thread per (b,s) row.
// ---------------------------------------------------------------------------
__global__ __launch_bounds__(256) void qkv_kernel(
    const float* __restrict__ x, const float* __restrict__ w,
    const float* __restrict__ bias, float* __restrict__ Q,
    float* __restrict__ K, float* __restrict__ V) {
  __shared__ float ws[DD * 3 * DD];  // w[in][out] row-major: ws[i*48 + o]
  __shared__ float bs[3 * DD];
  const int t = threadIdx.x;
  for (int idx = t; idx < DD * 3 * DD; idx += 256) ws[idx] = w[idx];
  if (t < 3 * DD) bs[t] = bias[t];
  __syncthreads();

  const int row = blockIdx.x * 256 + t;  // b*S + s
  const int b = row / SS;
  const int s = row % SS;

  float xr[DD];
  const float4* xp = (const float4*)(x + (size_t)row * DD);
#pragma unroll
  for (int i = 0; i < 4; ++i) {
    float4 v4 = xp[i];
    xr[4 * i + 0] = v4.x; xr[4 * i + 1] = v4.y;
    xr[4 * i + 2] = v4.z; xr[4 * i + 3] = v4.w;
  }

  for (int h = 0; h < HH; ++h) {
    float q = bs[h], k = bs[DD + h], v = bs[2 * DD + h];
#pragma unroll
    for (int i = 0; i < DD; ++i) {
      const float xv = xr[i];
      q = fmaf(xv, ws[i * 48 + h], q);
      k = fmaf(xv, ws[i * 48 + DD + h], k);
      v = fmaf(xv, ws[i * 48 + 2 * DD + h], v);
    }
    const int o = (b * HH + h) * SS + s;  // [b][h][s] — coalesced in s
    Q[o] = q; K[o] = k; V[o] = v;
  }
}

// ---------------------------------------------------------------------------
// Kernel B: causal softmax attention with head_size == 1.
// out[b,h,i] = sum_{j<=i} exp(q_i k_j) v_j / sum_{j<=i} exp(q_i k_j)
// grid = B*H*NCHUNK = 512 blocks, 256 threads.
// Each wave handles 64 consecutive queries; spans {c, 15-c, 16+c, 31-c}
// give every block identical total work.
// ---------------------------------------------------------------------------
__global__ __launch_bounds__(256) void attn_kernel(
    const float* __restrict__ Q, const float* __restrict__ K,
    const float* __restrict__ V, float* __restrict__ AO) {
  __shared__ float Kl[SS];
  __shared__ float Vl[SS];
  const int c = blockIdx.x & (NCHUNK - 1);
  const int bh = blockIdx.x >> 3;  // 0..63
  const int b = bh >> 4, h = bh & 15;
  const int t = threadIdx.x;

  // Stage this (b,h)'s K,V rows (8 KB each) into LDS, float4-coalesced.
  const float4* Kg = (const float4*)(K + (size_t)bh * SS);
  const float4* Vg = (const float4*)(V + (size_t)bh * SS);
  float4* Kl4 = (float4*)Kl;
  float4* Vl4 = (float4*)Vl;
  for (int idx = t; idx < SS / 4; idx += 256) {
    Kl4[idx] = Kg[idx];
    Vl4[idx] = Vg[idx];
  }
  __syncthreads();

  const int w = t >> 6, lane = t & 63;
  const int span = (w == 0) ? c : (w == 1) ? (15 - c) : (w == 2) ? (16 + c) : (31 - c);
  const int i = span * 64 + lane;  // query index, consecutive within the wave

  // Fold log2(e) into q: exp(q*k) = exp2(qs*k).
  const float qs = Q[bh * SS + i] * LOG2E;

  float l0 = 0.f, l1 = 0.f, l2 = 0.f, l3 = 0.f;
  float a0 = 0.f, a1 = 0.f, a2 = 0.f, a3 = 0.f;
  int j = 0;
  const int n4 = (i + 1) & ~3;
  for (; j < n4; j += 4) {  // broadcast LDS reads (all lanes same addr): free
    const float4 k4 = Kl4[j >> 2];
    const float4 v4 = Vl4[j >> 2];
    const float e0 = EXP2(qs * k4.x);
    const float e1 = EXP2(qs * k4.y);
    const float e2 = EXP2(qs * k4.z);
    const float e3 = EXP2(qs * k4.w);
    l0 += e0; l1 += e1; l2 += e2; l3 += e3;
    a0 = fmaf(e0, v4.x, a0);
    a1 = fmaf(e1, v4.y, a1);
    a2 = fmaf(e2, v4.z, a2);
    a3 = fmaf(e3, v4.w, a3);
  }
  for (; j <= i; ++j) {
    const float e = EXP2(qs * Kl[j]);
    l0 += e;
    a0 = fmaf(e, Vl[j], a0);
  }
  const float l = (l0 + l1) + (l2 + l3);
  const float a = (a0 + a1) + (a2 + a3);
  // AO layout [b][s][h] so the projection kernel reads contiguous rows.
  AO[((size_t)b * SS + i) * HH + h] = a / l;
}

// ---------------------------------------------------------------------------
// Kernel C: out = AO @ w_out + b_out. One thread per (b,s) row.
// grid = 32 blocks, 256 threads.
// ---------------------------------------------------------------------------
__global__ __launch_bounds__(256) void proj_kernel(
    const float* __restrict__ AO, const float* __restrict__ w,
    const float* __restrict__ bias, float* __restrict__ out) {
  __shared__ float ws[DD * DD];
  __shared__ float bs[DD];
  const int t = threadIdx.x;
  if (t < DD * DD) ws[t] = w[t];
  if (t < DD) bs[t] = bias[t];
  __syncthreads();

  const int row = blockIdx.x * 256 + t;  // b*S + s
  float xr[DD];
  const float4* xp = (const float4*)(AO + (size_t)row * DD);
#pragma unroll
  for (int i = 0; i < 4; ++i) {
    float4 v4 = xp[i];
    xr[4 * i + 0] = v4.x; xr[4 * i + 1] = v4.y;
    xr[4 * i + 2] = v4.z; xr[4 * i + 3] = v4.w;
  }

  float y[DD];
#pragma unroll
  for (int d = 0; d < DD; ++d) y[d] = bs[d];
#pragma unroll
  for (int i = 0; i < DD; ++i) {
    const float xv = xr[i];
#pragma unroll
    for (int d = 0; d < DD; ++d) y[d] = fmaf(xv, ws[i * DD + d], y[d]);
  }

  float4* op = (float4*)(out + (size_t)row * DD);
#pragma unroll
  for (int i = 0; i < 4; ++i) {
    float4 v4;
    v4.x = y[4 * i + 0]; v4.y = y[4 * i + 1];
    v4.z = y[4 * i + 2]; v4.w = y[4 * i + 3];
    op[i] = v4;
  }
}

// ---------------------------------------------------------------------------
extern "C" void kernel_launch(void* const* d_in, const int* in_sizes, int n_in,
                              void* d_out, int out_size, void* d_ws,
                              size_t ws_size, hipStream_t stream) {
  const float* x = (const float*)d_in[0];       // [B,S,D]
  const float* w_qkv = (const float*)d_in[1];   // [D, 3D]
  const float* b_qkv = (const float*)d_in[2];   // [3D]
  const float* w_out = (const float*)d_in[3];   // [D, D]
  const float* b_out = (const float*)d_in[4];   // [D]
  float* out = (float*)d_out;                   // [B,S,D] fp32

  float* ws = (float*)d_ws;
  float* Q = ws;             // [B][H][S]
  float* K = ws + BHS;       // [B][H][S]
  float* V = ws + 2 * BHS;   // [B][H][S]
  float* AO = ws + 3 * BHS;  // [B][S][H]

  qkv_kernel<<<(BB * SS) / 256, 256, 0, stream>>>(x, w_qkv, b_qkv, Q, K, V);
  attn_kernel<<<BB * HH * NCHUNK, 256, 0, stream>>>(Q, K, V, AO);
  proj_kernel<<<(BB * SS) / 256, 256, 0, stream>>>(AO, w_out, b_out, out);
}